// Round 1
// baseline (815.568 us; speedup 1.0000x reference)
//
#include <hip/hip_runtime.h>
#include <math.h>
#include <stdint.h>

// ---------------------------------------------------------------------------
// MalaAttention on MI355X (gfx950).
// Strategy: bf16 MFMA for all GEMM-shaped work (threshold admits bf16),
// m97-style NT GEMM (128x128 tile, BK=32, global_load_lds width=16).
//
// Workspace layout (bytes):
//   Xb    @ 0          32MB  bf16 X           (reused as P after proj GEMM)
//   Wcat  @ 33554432    8MB  bf16 [Wq;Wk;Wv;Wg] rows 0..4095
//   Wob   @ 41943040    2MB  bf16 Wo
//   QKVG  @ 44040192  128MB  bf16 [16384][4096] col blocks: q|k|v|g
//   kvf   @ 178257920   2MB  f32 kv[bh][d][e]
//   ksum  @ 180355072  16KB  f32 [bh][128]
//   vsum  @ 180371456  16KB  f32 [bh][128]
//   kvT   @ 180387840   1MB  bf16 kvT[bh][e][d]
//   den   @ 181436416 512KB  f32 [16384][8]
//   obuf  @ 181960704  32MB  bf16 gated output (input of final GEMM)
//   total 215515136 (~206MB)
// ---------------------------------------------------------------------------

typedef __bf16 bf16;
typedef __bf16 bf16x2 __attribute__((ext_vector_type(2)));
typedef __bf16 bf16x4 __attribute__((ext_vector_type(4)));
typedef __bf16 bf16x8 __attribute__((ext_vector_type(8)));
typedef float f32x4 __attribute__((ext_vector_type(4)));

static constexpr float kScale = 0.08838834764831845f; // 1/sqrt(128)

__device__ __forceinline__ void async_copy16(const void* g, void* l) {
  __builtin_amdgcn_global_load_lds(
      (const __attribute__((address_space(1))) void*)(uintptr_t)g,
      (__attribute__((address_space(3))) void*)(uintptr_t)l, 16, 0, 0);
}

// ---------------------------------------------------------------------------
// NT GEMM: C[m][n] = sum_k A[m][k] * B[n][k]  (A,B bf16 row-major along K)
// block = 256 thr (4 waves), tile 128x128, BK=32, one wave -> 64x64 quadrant.
// Per-block offsets: base + blockIdx.z*{A,B,C}z + blockIdx.y*{A,B,C}y.
// ---------------------------------------------------------------------------
template <typename OutT>
__global__ __launch_bounds__(256, 2) void gemm_nt(
    const bf16* __restrict__ A, long lda, long Az, long Ay,
    const bf16* __restrict__ Bm, long ldb, long Bz, long By,
    OutT* __restrict__ C, long ldc, long Cz, long Cy, int K)
{
  __shared__ __align__(16) bf16 As[128 * 32];
  __shared__ __align__(16) bf16 Bs[128 * 32];
  const int t = threadIdx.x;
  const long m0 = (long)blockIdx.x * 128;
  A  += (long)blockIdx.z * Az + (long)blockIdx.y * Ay + m0 * lda;
  Bm += (long)blockIdx.z * Bz + (long)blockIdx.y * By;
  C  += (long)blockIdx.z * Cz + (long)blockIdx.y * Cy + m0 * ldc;

  // staging: 128x32 bf16 = 8KB = 512 x 16B chunks; 256 threads x 2 issues.
  const int i0 = t, i1 = t + 256;
  const bf16* gA0 = A  + (long)(i0 >> 2) * lda + (i0 & 3) * 8;
  const bf16* gA1 = A  + (long)(i1 >> 2) * lda + (i1 & 3) * 8;
  const bf16* gB0 = Bm + (long)(i0 >> 2) * ldb + (i0 & 3) * 8;
  const bf16* gB1 = Bm + (long)(i1 >> 2) * ldb + (i1 & 3) * 8;
  bf16* lA0 = As + i0 * 8; bf16* lA1 = As + i1 * 8;
  bf16* lB0 = Bs + i0 * 8; bf16* lB1 = Bs + i1 * 8;

  const int lane = t & 63, wv = t >> 6;
  const int moff = (wv & 1) * 64, noff = (wv >> 1) * 64;
  const int fm = lane & 15, fq = lane >> 4;

  f32x4 acc[4][4] = {};

  for (int k0 = 0; k0 < K; k0 += 32) {
    async_copy16(gA0, lA0); async_copy16(gA1, lA1);
    async_copy16(gB0, lB0); async_copy16(gB1, lB1);
    gA0 += 32; gA1 += 32; gB0 += 32; gB1 += 32;
    __syncthreads();  // drains vmcnt -> LDS valid
    bf16x8 af[4], bfv[4];
#pragma unroll
    for (int i = 0; i < 4; ++i) {
      af[i]  = *(const bf16x8*)(As + (moff + i * 16 + fm) * 32 + fq * 8);
      bfv[i] = *(const bf16x8*)(Bs + (noff + i * 16 + fm) * 32 + fq * 8);
    }
#pragma unroll
    for (int i = 0; i < 4; ++i)
#pragma unroll
      for (int j = 0; j < 4; ++j)
        acc[i][j] = __builtin_amdgcn_mfma_f32_16x16x32_bf16(af[i], bfv[j], acc[i][j], 0, 0, 0);
    __syncthreads();  // protect LDS before next overwrite
  }

  // C/D layout: col = lane&15, row = (lane>>4)*4 + reg  [m89/m91 verified]
#pragma unroll
  for (int i = 0; i < 4; ++i)
#pragma unroll
    for (int j = 0; j < 4; ++j)
#pragma unroll
      for (int r = 0; r < 4; ++r) {
        const long row = moff + i * 16 + fq * 4 + r;
        const long col = noff + j * 16 + fm;
        C[row * ldc + col] = (OutT)acc[i][j][r];
      }
}

// ---------------------------------------------------------------------------
__global__ void cast_x(const float* __restrict__ X, bf16* __restrict__ Xb) {
  long g = ((long)blockIdx.x * 256 + threadIdx.x) * 4;
  float4 v = *(const float4*)(X + g);
  bf16x4 o = {(bf16)v.x, (bf16)v.y, (bf16)v.z, (bf16)v.w};
  *(bf16x4*)(Xb + g) = o;
}

__global__ void cast_w(const float* __restrict__ Wq, const float* __restrict__ Wk,
                       const float* __restrict__ Wv, const float* __restrict__ Wg,
                       const float* __restrict__ Wo, bf16* __restrict__ Wcat,
                       bf16* __restrict__ Wob)
{
  long g = ((long)blockIdx.x * 256 + threadIdx.x) * 4;
  if (g < 4194304) {
    long idx = g & 1048575;
    int sel = (int)(g >> 20);
    const float* s = sel == 0 ? Wq : sel == 1 ? Wk : sel == 2 ? Wv : Wg;
    float4 v = *(const float4*)(s + idx);
    bf16x4 o = {(bf16)v.x, (bf16)v.y, (bf16)v.z, (bf16)v.w};
    *(bf16x4*)(Wcat + g) = o;
  } else {
    long idx = g - 4194304;
    float4 v = *(const float4*)(Wo + idx);
    bf16x4 o = {(bf16)v.x, (bf16)v.y, (bf16)v.z, (bf16)v.w};
    *(bf16x4*)(Wob + idx) = o;
  }
}

// In-place RoPE on q (cols 0..1023) and k (cols 1024..2047) of QKVG.
__global__ void rope_kernel(bf16* __restrict__ QKVG) {
  long g = (long)blockIdx.x * 256 + threadIdx.x;   // B*S*H*64 = 8388608
  int i = (int)(g & 63);
  long rem = g >> 6;
  int h = (int)(rem & 7); rem >>= 3;
  int s = (int)(rem & 4095);
  int b = (int)(rem >> 12);
  float inv = powf(10000.0f, -((float)(2 * i)) / 128.0f);
  float ang = (float)s * inv;
  float sn, cs;
  sincosf(ang, &sn, &cs);
  long row = ((long)b * 4096 + s) * 4096;
#pragma unroll
  for (int blk = 0; blk < 2; ++blk) {
    long c0 = row + blk * 1024 + h * 128 + i;
    float x1 = (float)QKVG[c0], x2 = (float)QKVG[c0 + 64];
    QKVG[c0]      = (bf16)(x1 * cs - x2 * sn);
    QKVG[c0 + 64] = (bf16)(x2 * cs + x1 * sn);
  }
}

// kv[bh][d][e] += sum_s k[s][d]*v[s][e]; also ksum, vsum. Split-S, atomics.
// grid (32, 16): 256-row s chunks. thread (ty,tx) owns d:ty*8+, e:tx*8+.
__global__ void kv_accum(const bf16* __restrict__ QKVG, float* __restrict__ kvf,
                         float* __restrict__ ksum, float* __restrict__ vsum)
{
  const int bh = blockIdx.x, b = bh >> 3, h = bh & 7;
  const int t = threadIdx.x, tx = t & 15, ty = t >> 4;
  const long s0 = (long)blockIdx.y * 256;
  const bf16* kp = QKVG + ((long)b * 4096 + s0) * 4096 + 1024 + h * 128 + ty * 8;
  const bf16* vp = QKVG + ((long)b * 4096 + s0) * 4096 + 2048 + h * 128 + tx * 8;
  float acc[8][8] = {};
  float ks[8] = {}, vs[8] = {};
  for (int s = 0; s < 256; ++s) {
    bf16x8 k8 = *(const bf16x8*)kp;
    bf16x8 v8 = *(const bf16x8*)vp;
    kp += 4096; vp += 4096;
    float kf[8], vf[8];
#pragma unroll
    for (int i = 0; i < 8; ++i) { kf[i] = (float)k8[i]; vf[i] = (float)v8[i]; }
#pragma unroll
    for (int i = 0; i < 8; ++i)
#pragma unroll
      for (int j = 0; j < 8; ++j) acc[i][j] += kf[i] * vf[j];
    if (tx == 0) {
#pragma unroll
      for (int i = 0; i < 8; ++i) ks[i] += kf[i];
    }
    if (ty == 0) {
#pragma unroll
      for (int j = 0; j < 8; ++j) vs[j] += vf[j];
    }
  }
  float* kb = kvf + ((long)bh * 128 + ty * 8) * 128 + tx * 8;
#pragma unroll
  for (int i = 0; i < 8; ++i)
#pragma unroll
    for (int j = 0; j < 8; ++j) atomicAdd(&kb[i * 128 + j], acc[i][j]);
  if (tx == 0) {
#pragma unroll
    for (int i = 0; i < 8; ++i) atomicAdd(&ksum[bh * 128 + ty * 8 + i], ks[i]);
  }
  if (ty == 0) {
#pragma unroll
    for (int j = 0; j < 8; ++j) atomicAdd(&vsum[bh * 128 + tx * 8 + j], vs[j]);
  }
}

// kvT[bh][e][d] = (bf16) kvf[bh][d][e]
__global__ void kv_finalize(const float* __restrict__ kvf, bf16* __restrict__ kvT) {
  long g = (long)blockIdx.x * 256 + threadIdx.x;   // 524288
  long bh = g >> 14;
  int d = (int)((g >> 7) & 127), e = (int)(g & 127);
  kvT[(bh << 14) + (long)e * 128 + d] = (bf16)kvf[g];
}

// den[r][h] = scale * q[r,h,:].ksum[b,h,:] + S ; one wave per (r,h).
__global__ void den_kernel(const bf16* __restrict__ QKVG, const float* __restrict__ ksum,
                           float* __restrict__ den)
{
  const int t = threadIdx.x, lane = t & 63;
  const long gw = (long)blockIdx.x * 4 + (t >> 6);  // 131072 waves
  const long r = gw >> 3;
  const int h = (int)(gw & 7);
  const int b = (int)(r >> 12);
  bf16x2 q2 = *(const bf16x2*)(QKVG + r * 4096 + h * 128 + lane * 2);
  float2 k2 = *(const float2*)(ksum + (b * 8 + h) * 128 + lane * 2);
  float p = (float)q2[0] * k2.x + (float)q2[1] * k2.y;
#pragma unroll
  for (int o = 32; o > 0; o >>= 1) p += __shfl_xor(p, o, 64);
  if (lane == 0) den[r * 8 + h] = p * kScale + 4096.0f;
}

// o = ((P*scale + vsum)/den + lepe_conv(v)) * g   -> bf16 obuf
__global__ void fuse_kernel(const bf16* __restrict__ P, const bf16* __restrict__ QKVG,
                            const float* __restrict__ vsum, const float* __restrict__ den,
                            const float* __restrict__ lepe_w, const float* __restrict__ lepe_b,
                            bf16* __restrict__ obuf)
{
  long g = (long)blockIdx.x * 256 + threadIdx.x;   // 16777216
  int c = (int)(g & 1023);
  long r = g >> 10;
  int h = c >> 7, e = c & 127;
  int s = (int)(r & 4095), b = (int)(r >> 12);
  float num = (float)P[g] * kScale + vsum[(b * 8 + h) * 128 + e];
  float attn = num / den[r * 8 + h];
  float lep = lepe_b[c];
  const bf16* vcol = QKVG + r * 4096 + 2048 + c;
#pragma unroll
  for (int j = 0; j < 5; ++j) {
    int ssj = s + j - 2;
    if (ssj >= 0 && ssj < 4096) lep += (float)vcol[(long)(j - 2) * 4096] * lepe_w[c * 5 + j];
  }
  float gate = (float)QKVG[r * 4096 + 3072 + c];
  obuf[g] = (bf16)((attn + lep) * gate);
}

// ---------------------------------------------------------------------------
extern "C" void kernel_launch(void* const* d_in, const int* in_sizes, int n_in,
                              void* d_out, int out_size, void* d_ws, size_t ws_size,
                              hipStream_t stream)
{
  const float* X      = (const float*)d_in[0];
  const float* Wq     = (const float*)d_in[1];
  const float* Wk     = (const float*)d_in[2];
  const float* Wv     = (const float*)d_in[3];
  const float* Wg     = (const float*)d_in[4];
  const float* Wo     = (const float*)d_in[5];
  const float* lepe_w = (const float*)d_in[6];
  const float* lepe_b = (const float*)d_in[7];
  float* out = (float*)d_out;

  char* ws = (char*)d_ws;
  bf16*  Xb   = (bf16*)(ws);
  bf16*  Wcat = (bf16*)(ws + 33554432);
  bf16*  Wob  = (bf16*)(ws + 41943040);
  bf16*  QKVG = (bf16*)(ws + 44040192);
  float* kvf  = (float*)(ws + 178257920);
  float* ksum = (float*)(ws + 180355072);
  float* vsum = (float*)(ws + 180371456);
  bf16*  kvT  = (bf16*)(ws + 180387840);
  float* den  = (float*)(ws + 181436416);
  bf16*  obuf = (bf16*)(ws + 181960704);
  bf16*  P    = Xb;  // Xb dead after proj GEMM

  // zero kv accumulators (kvf + ksum + vsum are contiguous)
  hipMemsetAsync(kvf, 0, 2097152 + 32768, stream);

  cast_x<<<16384, 256, 0, stream>>>(X, Xb);
  cast_w<<<5120, 256, 0, stream>>>(Wq, Wk, Wv, Wg, Wo, Wcat, Wob);

  // QKVG = Xb @ Wcat^T : M=16384 N=4096 K=1024
  gemm_nt<bf16><<<dim3(128, 32, 1), 256, 0, stream>>>(
      Xb, 1024, 0, 0, Wcat, 1024, 0, 131072, QKVG, 4096, 0, 128, 1024);

  rope_kernel<<<32768, 256, 0, stream>>>(QKVG);

  kv_accum<<<dim3(32, 16), 256, 0, stream>>>(QKVG, kvf, ksum, vsum);
  kv_finalize<<<2048, 256, 0, stream>>>(kvf, kvT);
  den_kernel<<<32768, 256, 0, stream>>>(QKVG, ksum, den);

  // P[b] (s,e per head) = q @ kvT^T : per (b,h): M=4096 N=128 K=128
  gemm_nt<bf16><<<dim3(32, 8, 4), 256, 0, stream>>>(
      QKVG, 4096, 16777216, 128, kvT, 128, 131072, 16384, P, 1024, 4194304, 128, 128);

  fuse_kernel<<<65536, 256, 0, stream>>>(P, QKVG, vsum, den, lepe_w, lepe_b, obuf);

  // out = obuf @ Wob^T : M=16384 N=1024 K=1024, fp32 out
  gemm_nt<float><<<dim3(128, 8, 1), 256, 0, stream>>>(
      obuf, 1024, 0, 0, Wob, 1024, 0, 131072, out, 1024, 0, 128, 1024);
}

// Round 2
// 523.026 us; speedup vs baseline: 1.5593x; 1.5593x over previous
//
#include <hip/hip_runtime.h>
#include <math.h>
#include <stdint.h>

// ---------------------------------------------------------------------------
// MalaAttention on MI355X (gfx950). Round 2: kv path via MFMA + partials
// (no atomics); kv_accum (350us, atomic-RMW-bound) removed.
//
// Workspace layout (bytes):
//   Xb    @ 0          32MB  bf16 X           (reused as P after proj GEMM)
//   Wcat  @ 33554432    8MB  bf16 [Wq;Wk;Wv;Wg]
//   Wob   @ 41943040    2MB  bf16 Wo
//   QKVG  @ 44040192  128MB  bf16 [16384][4096] col blocks: q|k|v|g
//   ksum  @ 180355072  16KB  f32 [bh][128]
//   vsum  @ 180371456  16KB  f32 [bh][128]
//   kvT   @ 180387840   1MB  bf16 kvT[bh][e][d]
//   sums  @ 181436416 512KB  f32 ksump/vsump partials (dead before den wr)
//   den   @ 181436416 512KB  f32 [16384][8]   (aliases sums; sums die first)
//   obuf  @ 181960704  32MB  bf16 gated out   (aliases kvp; kvp dies first)
//   kvp   @ 181960704  32MB  f32 [16][bh][128][128] partials
// ---------------------------------------------------------------------------

typedef __bf16 bf16;
typedef __bf16 bf16x2 __attribute__((ext_vector_type(2)));
typedef __bf16 bf16x4 __attribute__((ext_vector_type(4)));
typedef __bf16 bf16x8 __attribute__((ext_vector_type(8)));
typedef float f32x4 __attribute__((ext_vector_type(4)));

static constexpr float kScale = 0.08838834764831845f; // 1/sqrt(128)

__device__ __forceinline__ void async_copy16(const void* g, void* l) {
  __builtin_amdgcn_global_load_lds(
      (const __attribute__((address_space(1))) void*)(uintptr_t)g,
      (__attribute__((address_space(3))) void*)(uintptr_t)l, 16, 0, 0);
}

// ---------------------------------------------------------------------------
// NT GEMM: C[m][n] = sum_k A[m][k] * B[n][k]  (A,B bf16 row-major along K)
// block = 256 thr (4 waves), tile 128x128, BK=32, one wave -> 64x64 quadrant.
// ---------------------------------------------------------------------------
template <typename OutT>
__global__ __launch_bounds__(256, 2) void gemm_nt(
    const bf16* __restrict__ A, long lda, long Az, long Ay,
    const bf16* __restrict__ Bm, long ldb, long Bz, long By,
    OutT* __restrict__ C, long ldc, long Cz, long Cy, int K)
{
  __shared__ __align__(16) bf16 As[128 * 32];
  __shared__ __align__(16) bf16 Bs[128 * 32];
  const int t = threadIdx.x;
  const long m0 = (long)blockIdx.x * 128;
  A  += (long)blockIdx.z * Az + (long)blockIdx.y * Ay + m0 * lda;
  Bm += (long)blockIdx.z * Bz + (long)blockIdx.y * By;
  C  += (long)blockIdx.z * Cz + (long)blockIdx.y * Cy + m0 * ldc;

  const int i0 = t, i1 = t + 256;
  const bf16* gA0 = A  + (long)(i0 >> 2) * lda + (i0 & 3) * 8;
  const bf16* gA1 = A  + (long)(i1 >> 2) * lda + (i1 & 3) * 8;
  const bf16* gB0 = Bm + (long)(i0 >> 2) * ldb + (i0 & 3) * 8;
  const bf16* gB1 = Bm + (long)(i1 >> 2) * ldb + (i1 & 3) * 8;
  bf16* lA0 = As + i0 * 8; bf16* lA1 = As + i1 * 8;
  bf16* lB0 = Bs + i0 * 8; bf16* lB1 = Bs + i1 * 8;

  const int lane = t & 63, wv = t >> 6;
  const int moff = (wv & 1) * 64, noff = (wv >> 1) * 64;
  const int fm = lane & 15, fq = lane >> 4;

  f32x4 acc[4][4] = {};

  for (int k0 = 0; k0 < K; k0 += 32) {
    async_copy16(gA0, lA0); async_copy16(gA1, lA1);
    async_copy16(gB0, lB0); async_copy16(gB1, lB1);
    gA0 += 32; gA1 += 32; gB0 += 32; gB1 += 32;
    __syncthreads();
    bf16x8 af[4], bfv[4];
#pragma unroll
    for (int i = 0; i < 4; ++i) {
      af[i]  = *(const bf16x8*)(As + (moff + i * 16 + fm) * 32 + fq * 8);
      bfv[i] = *(const bf16x8*)(Bs + (noff + i * 16 + fm) * 32 + fq * 8);
    }
#pragma unroll
    for (int i = 0; i < 4; ++i)
#pragma unroll
      for (int j = 0; j < 4; ++j)
        acc[i][j] = __builtin_amdgcn_mfma_f32_16x16x32_bf16(af[i], bfv[j], acc[i][j], 0, 0, 0);
    __syncthreads();
  }

#pragma unroll
  for (int i = 0; i < 4; ++i)
#pragma unroll
    for (int j = 0; j < 4; ++j)
#pragma unroll
      for (int r = 0; r < 4; ++r) {
        const long row = moff + i * 16 + fq * 4 + r;
        const long col = noff + j * 16 + fm;
        C[row * ldc + col] = (OutT)acc[i][j][r];
      }
}

// ---------------------------------------------------------------------------
__global__ void cast_x(const float* __restrict__ X, bf16* __restrict__ Xb) {
  long g = ((long)blockIdx.x * 256 + threadIdx.x) * 4;
  float4 v = *(const float4*)(X + g);
  bf16x4 o = {(bf16)v.x, (bf16)v.y, (bf16)v.z, (bf16)v.w};
  *(bf16x4*)(Xb + g) = o;
}

__global__ void cast_w(const float* __restrict__ Wq, const float* __restrict__ Wk,
                       const float* __restrict__ Wv, const float* __restrict__ Wg,
                       const float* __restrict__ Wo, bf16* __restrict__ Wcat,
                       bf16* __restrict__ Wob)
{
  long g = ((long)blockIdx.x * 256 + threadIdx.x) * 4;
  if (g < 4194304) {
    long idx = g & 1048575;
    int sel = (int)(g >> 20);
    const float* s = sel == 0 ? Wq : sel == 1 ? Wk : sel == 2 ? Wv : Wg;
    float4 v = *(const float4*)(s + idx);
    bf16x4 o = {(bf16)v.x, (bf16)v.y, (bf16)v.z, (bf16)v.w};
    *(bf16x4*)(Wcat + g) = o;
  } else {
    long idx = g - 4194304;
    float4 v = *(const float4*)(Wo + idx);
    bf16x4 o = {(bf16)v.x, (bf16)v.y, (bf16)v.z, (bf16)v.w};
    *(bf16x4*)(Wob + idx) = o;
  }
}

// In-place RoPE on q (cols 0..1023) and k (cols 1024..2047) of QKVG.
__global__ void rope_kernel(bf16* __restrict__ QKVG) {
  long g = (long)blockIdx.x * 256 + threadIdx.x;   // 8388608
  int i = (int)(g & 63);
  long rem = g >> 6;
  int h = (int)(rem & 7); rem >>= 3;
  int s = (int)(rem & 4095);
  int b = (int)(rem >> 12);
  float inv = powf(10000.0f, -((float)(2 * i)) / 128.0f);
  float ang = (float)s * inv;
  float sn, cs;
  sincosf(ang, &sn, &cs);
  long row = ((long)b * 4096 + s) * 4096;
#pragma unroll
  for (int blk = 0; blk < 2; ++blk) {
    long c0 = row + blk * 1024 + h * 128 + i;
    float x1 = (float)QKVG[c0], x2 = (float)QKVG[c0 + 64];
    QKVG[c0]      = (bf16)(x1 * cs - x2 * sn);
    QKVG[c0 + 64] = (bf16)(x2 * cs + x1 * sn);
  }
}

// ---------------------------------------------------------------------------
// kv via MFMA with in-LDS transpose. Grid (16 s-chunks, 32 bh), 256 thr.
// Computes per-chunk partials kvp[chunk][bh][e][d] = sum_s v[s][e] k[s][d]
// (i.e. kvT directly) + row-sum partials for ksum/vsum. No atomics.
// LDS rows padded to 40 elems: 80B stride -> 16B-aligned b128 fragments.
// ---------------------------------------------------------------------------
__global__ __launch_bounds__(256, 2) void kv_mfma(
    const bf16* __restrict__ QKVG, float* __restrict__ kvp,
    float* __restrict__ ksump, float* __restrict__ vsump)
{
  __shared__ __align__(16) bf16 VT[128 * 40];
  __shared__ __align__(16) bf16 KT[128 * 40];
  const int t = threadIdx.x;
  const int chunk = blockIdx.x, bh = blockIdx.y;
  const int b = bh >> 3, h = bh & 7;
  const long rowbase = ((long)b * 4096 + chunk * 256) * 4096 + h * 128;
  const bf16* Kg = QKVG + rowbase + 1024;
  const bf16* Vg = QKVG + rowbase + 2048;

  const int sp = t >> 4, fc = t & 15;      // staging: s-pair, feature octet
  const int lane = t & 63, wv = t >> 6;
  const int eoff = (wv & 1) * 64, doff = (wv >> 1) * 64;
  const int fm = lane & 15, fq = lane >> 4;
  const int srow = t & 127;                // row-sum assignment
  const bool sumK = t >= 128;

  f32x4 acc[4][4] = {};
  float rsum = 0.f;

  for (int sb = 0; sb < 256; sb += 32) {
    const long go = (long)(sb + 2 * sp) * 4096 + fc * 8;
    bf16x8 v0 = *(const bf16x8*)(Vg + go);
    bf16x8 v1 = *(const bf16x8*)(Vg + go + 4096);
    bf16x8 k0 = *(const bf16x8*)(Kg + go);
    bf16x8 k1 = *(const bf16x8*)(Kg + go + 4096);
#pragma unroll
    for (int j = 0; j < 8; ++j) {
      const int f = fc * 8 + j;
      bf16x2 vp2 = {v0[j], v1[j]};
      bf16x2 kp2 = {k0[j], k1[j]};
      *(bf16x2*)(VT + f * 40 + 2 * sp) = vp2;
      *(bf16x2*)(KT + f * 40 + 2 * sp) = kp2;
    }
    __syncthreads();
    bf16x8 af[4], bfv[4];
#pragma unroll
    for (int i = 0; i < 4; ++i) {
      af[i]  = *(const bf16x8*)(VT + (eoff + i * 16 + fm) * 40 + fq * 8);
      bfv[i] = *(const bf16x8*)(KT + (doff + i * 16 + fm) * 40 + fq * 8);
    }
#pragma unroll
    for (int i = 0; i < 4; ++i)
#pragma unroll
      for (int j = 0; j < 4; ++j)
        acc[i][j] = __builtin_amdgcn_mfma_f32_16x16x32_bf16(af[i], bfv[j], acc[i][j], 0, 0, 0);
    // ksum/vsum partials from the staged (transposed) tiles
    const bf16* rp = (sumK ? KT : VT) + srow * 40;
#pragma unroll
    for (int i = 0; i < 4; ++i) {
      bf16x8 r8 = *(const bf16x8*)(rp + i * 8);
#pragma unroll
      for (int j = 0; j < 8; ++j) rsum += (float)r8[j];
    }
    __syncthreads();
  }

  float* plane = kvp + ((long)chunk * 32 + bh) * 16384;
#pragma unroll
  for (int i = 0; i < 4; ++i)
#pragma unroll
    for (int j = 0; j < 4; ++j)
#pragma unroll
      for (int r = 0; r < 4; ++r)
        plane[(long)(eoff + i * 16 + fq * 4 + r) * 128 + (doff + j * 16 + fm)] = acc[i][j][r];
  float* sdst = (sumK ? ksump : vsump) + ((long)chunk * 32 + bh) * 128 + srow;
  *sdst = rsum;
}

// Fold 16 chunk partials -> bf16 kvT + f32 ksum/vsum.
__global__ void kv_reduce(const float* __restrict__ kvp, const float* __restrict__ ksump,
                          const float* __restrict__ vsump, bf16* __restrict__ kvT,
                          float* __restrict__ ksum, float* __restrict__ vsum)
{
  long g = (long)blockIdx.x * 256 + threadIdx.x;  // 524288
  long bh = g >> 14, idx = g & 16383;
  float s = 0.f;
#pragma unroll
  for (int c = 0; c < 16; ++c) s += kvp[((long)c * 32 + bh) * 16384 + idx];
  kvT[g] = (bf16)s;
  if (g < 8192) {
    int bh2 = (int)(g >> 8), rem = (int)(g & 255), f = rem & 127;
    const float* src = (rem >> 7) ? ksump : vsump;
    float* dst = (rem >> 7) ? ksum : vsum;
    float s2 = 0.f;
#pragma unroll
    for (int c = 0; c < 16; ++c) s2 += src[((long)c * 32 + bh2) * 128 + f];
    dst[bh2 * 128 + f] = s2;
  }
}

// den[r][h] = scale * q[r,h,:].ksum[b,h,:] + S ; one wave per (r,h).
__global__ void den_kernel(const bf16* __restrict__ QKVG, const float* __restrict__ ksum,
                           float* __restrict__ den)
{
  const int t = threadIdx.x, lane = t & 63;
  const long gw = (long)blockIdx.x * 4 + (t >> 6);  // 131072 waves
  const long r = gw >> 3;
  const int h = (int)(gw & 7);
  const int b = (int)(r >> 12);
  bf16x2 q2 = *(const bf16x2*)(QKVG + r * 4096 + h * 128 + lane * 2);
  float2 k2 = *(const float2*)(ksum + (b * 8 + h) * 128 + lane * 2);
  float p = (float)q2[0] * k2.x + (float)q2[1] * k2.y;
#pragma unroll
  for (int o = 32; o > 0; o >>= 1) p += __shfl_xor(p, o, 64);
  if (lane == 0) den[r * 8 + h] = p * kScale + 4096.0f;
}

// o = ((P*scale + vsum)/den + lepe_conv(v)) * g   -> bf16 obuf
__global__ void fuse_kernel(const bf16* __restrict__ P, const bf16* __restrict__ QKVG,
                            const float* __restrict__ vsum, const float* __restrict__ den,
                            const float* __restrict__ lepe_w, const float* __restrict__ lepe_b,
                            bf16* __restrict__ obuf)
{
  long g = (long)blockIdx.x * 256 + threadIdx.x;   // 16777216
  int c = (int)(g & 1023);
  long r = g >> 10;
  int h = c >> 7, e = c & 127;
  int s = (int)(r & 4095), b = (int)(r >> 12);
  float num = (float)P[g] * kScale + vsum[(b * 8 + h) * 128 + e];
  float attn = num / den[r * 8 + h];
  float lep = lepe_b[c];
  const bf16* vcol = QKVG + r * 4096 + 2048 + c;
#pragma unroll
  for (int j = 0; j < 5; ++j) {
    int ssj = s + j - 2;
    if (ssj >= 0 && ssj < 4096) lep += (float)vcol[(long)(j - 2) * 4096] * lepe_w[c * 5 + j];
  }
  float gate = (float)QKVG[r * 4096 + 3072 + c];
  obuf[g] = (bf16)((attn + lep) * gate);
}

// ---------------------------------------------------------------------------
extern "C" void kernel_launch(void* const* d_in, const int* in_sizes, int n_in,
                              void* d_out, int out_size, void* d_ws, size_t ws_size,
                              hipStream_t stream)
{
  const float* X      = (const float*)d_in[0];
  const float* Wq     = (const float*)d_in[1];
  const float* Wk     = (const float*)d_in[2];
  const float* Wv     = (const float*)d_in[3];
  const float* Wg     = (const float*)d_in[4];
  const float* Wo     = (const float*)d_in[5];
  const float* lepe_w = (const float*)d_in[6];
  const float* lepe_b = (const float*)d_in[7];
  float* out = (float*)d_out;

  char* ws = (char*)d_ws;
  bf16*  Xb    = (bf16*)(ws);
  bf16*  Wcat  = (bf16*)(ws + 33554432);
  bf16*  Wob   = (bf16*)(ws + 41943040);
  bf16*  QKVG  = (bf16*)(ws + 44040192);
  float* ksum  = (float*)(ws + 180355072);
  float* vsum  = (float*)(ws + 180371456);
  bf16*  kvT   = (bf16*)(ws + 180387840);
  float* ksump = (float*)(ws + 181436416);            // dies before den write
  float* vsump = (float*)(ws + 181436416 + 262144);
  float* den   = (float*)(ws + 181436416);            // aliases ksump/vsump
  bf16*  obuf  = (bf16*)(ws + 181960704);
  float* kvp   = (float*)(ws + 181960704);            // aliases obuf; dies first
  bf16*  P     = Xb;  // Xb dead after proj GEMM

  cast_x<<<16384, 256, 0, stream>>>(X, Xb);
  cast_w<<<5120, 256, 0, stream>>>(Wq, Wk, Wv, Wg, Wo, Wcat, Wob);

  // QKVG = Xb @ Wcat^T : M=16384 N=4096 K=1024
  gemm_nt<bf16><<<dim3(128, 32, 1), 256, 0, stream>>>(
      Xb, 1024, 0, 0, Wcat, 1024, 0, 131072, QKVG, 4096, 0, 128, 1024);

  rope_kernel<<<32768, 256, 0, stream>>>(QKVG);

  kv_mfma<<<dim3(16, 32), 256, 0, stream>>>(QKVG, kvp, ksump, vsump);
  kv_reduce<<<2048, 256, 0, stream>>>(kvp, ksump, vsump, kvT, ksum, vsum);
  den_kernel<<<32768, 256, 0, stream>>>(QKVG, ksum, den);

  // P (per b,h): M=4096 N=128 K=128
  gemm_nt<bf16><<<dim3(32, 8, 4), 256, 0, stream>>>(
      QKVG, 4096, 16777216, 128, kvT, 128, 131072, 16384, P, 1024, 4194304, 128, 128);

  fuse_kernel<<<65536, 256, 0, stream>>>(P, QKVG, vsum, den, lepe_w, lepe_b, obuf);

  // out = obuf @ Wob^T : M=16384 N=1024 K=1024, fp32 out
  gemm_nt<float><<<dim3(128, 8, 1), 256, 0, stream>>>(
      obuf, 1024, 0, 0, Wob, 1024, 0, 131072, out, 1024, 0, 128, 1024);
}